// Round 1
// baseline (423.173 us; speedup 1.0000x reference)
//
#include <hip/hip_runtime.h>
#include <math.h>

#define NUM_K 128
#define DIM   256
#define NROWS (64 * 2048)       // 131072
#define BLOCK 256
#define RPB   128               // rows per block
#define GRID  (NROWS / RPB)     // 1024

// flat fp32 output offsets (reference tuple order)
#define OFF_LOSS 0u
#define OFF_Q    1u
#define OFF_PERP 33554433u
#define OFF_ENC  33554434u
#define OFF_IDX  50331650u

// ws float layout: [0] loss acc; ints at float-idx [64..191] counts; floats [256..383] se[k]

typedef __attribute__((ext_vector_type(8))) short bf16x8;   // 8 bf16 (4 VGPRs)
typedef __attribute__((ext_vector_type(4))) float f32x4;    // MFMA acc
typedef float f4a __attribute__((ext_vector_type(4), aligned(4)));  // 4B-aligned stores (OFF_Q=1)

union PackU { uint4 u; bf16x8 v; };

__device__ __forceinline__ bf16x8 pack_hi16(const unsigned int* w) {
  PackU p;
  p.u.x = (w[1] & 0xFFFF0000u) | (w[0] >> 16);
  p.u.y = (w[3] & 0xFFFF0000u) | (w[2] >> 16);
  p.u.z = (w[5] & 0xFFFF0000u) | (w[4] >> 16);
  p.u.w = (w[7] & 0xFFFF0000u) | (w[6] >> 16);
  return p.v;
}

// Exact 3-way truncation split: x = a + b + c, all bf16-representable.
// a = top 8 mantissa bits; b = next 8 (r1 = x-a exact, 16-bit significand);
// c = r2 = r1-b exact with <=8 significant bits -> exactly a bf16.
__device__ __forceinline__ void split3(const float* xf, bf16x8& a, bf16x8& b, bf16x8& c) {
  unsigned int ua[8], ub[8], uc[8];
  #pragma unroll
  for (int i = 0; i < 8; ++i) {
    float x = xf[i];
    unsigned int ha = __float_as_uint(x) & 0xFFFF0000u;
    float r1 = x - __uint_as_float(ha);
    unsigned int hb = __float_as_uint(r1) & 0xFFFF0000u;
    float r2 = r1 - __uint_as_float(hb);
    ua[i] = ha; ub[i] = hb; uc[i] = __float_as_uint(r2);
  }
  a = pack_hi16(ua); b = pack_hi16(ub); c = pack_hi16(uc);
}

// 128 blocks x 64 lanes: block k computes ||e_k||^2; block 0 zeroes accumulators.
__global__ void vq_init(const float* __restrict__ E, float* __restrict__ ws) {
    int k = blockIdx.x, lane = threadIdx.x;
    float4 v = *(const float4*)(E + (size_t)k * DIM + lane * 4);
    float s = v.x * v.x + v.y * v.y + v.z * v.z + v.w * v.w;
    #pragma unroll
    for (int off = 32; off; off >>= 1) s += __shfl_down(s, off);
    if (lane == 0) ws[256 + k] = s;
    if (k == 0) {
        if (lane == 0) ws[0] = 0.0f;
        ((int*)ws)[64 + lane]  = 0;
        ((int*)ws)[128 + lane] = 0;
    }
}

// 1024 blocks x 256 threads (4 waves). Wave kg handles codes [kg*32, kg*32+32)
// for all 128 rows of the block via mfma_f32_16x16x32_bf16 with the 6-product
// exact split. A-frag: lane holds X[row=l&15][k=(l>>4)*8+j]. B-frag: lane holds
// E[code=c0+(l&15)][k=(l>>4)*8+j]. C/D: col=lane&15(code), row=(lane>>4)*4+reg.
__global__ __launch_bounds__(BLOCK, 2) void vq_main(
        const float* __restrict__ X, const float* __restrict__ E,
        float* ws, float* __restrict__ out) {
    const int tid  = threadIdx.x;
    const int lane = tid & 63;
    const int kg   = __builtin_amdgcn_readfirstlane(tid >> 6);   // 0..3, wave-uniform
    const int l4   = lane & 15;
    const int g    = lane >> 4;                                  // 0..3 k-group
    const int r0   = blockIdx.x * RPB;

    __shared__ float rd[4][RPB];
    __shared__ int   ri[4][RPB];
    __shared__ int   idxs[RPB];
    __shared__ int   hcnt[NUM_K];
    if (tid < NUM_K) hcnt[tid] = 0;

    const float* xp = X + (size_t)(r0 + l4) * DIM + g * 8;
    const float* ep = E + (size_t)(kg * 32 + l4) * DIM + g * 8;

    f32x4 acc[8][2];
    #pragma unroll
    for (int rt = 0; rt < 8; ++rt) {
        acc[rt][0] = (f32x4)0.0f;
        acc[rt][1] = (f32x4)0.0f;
    }
    float sx = 0.0f;

    #pragma unroll 1      // keep halves sequential: E-frag regs reused, no hoist
    for (int half = 0; half < 2; ++half) {
        const int kbase = half * 128;
        // ---- E fragments for this K-half: 2 col-tiles x 4 chunks x 3 splits ----
        bf16x8 ea[2][4], eb[2][4], ec[2][4];
        #pragma unroll
        for (int ct = 0; ct < 2; ++ct) {
            #pragma unroll
            for (int ch = 0; ch < 4; ++ch) {
                const float* p = ep + (size_t)ct * 16 * DIM + kbase + ch * 32;
                float4 v0 = *(const float4*)(p);
                float4 v1 = *(const float4*)(p + 4);
                float xf[8] = {v0.x, v0.y, v0.z, v0.w, v1.x, v1.y, v1.z, v1.w};
                split3(xf, ea[ct][ch], eb[ct][ch], ec[ct][ch]);
            }
        }
        // ---- 8 row-tiles x 4 chunks: load X, split, 12 MFMAs (2 indep acc chains) ----
        #pragma unroll
        for (int rt = 0; rt < 8; ++rt) {
            #pragma unroll
            for (int ch = 0; ch < 4; ++ch) {
                const float* p = xp + (size_t)rt * 16 * DIM + kbase + ch * 32;
                float4 v0 = *(const float4*)(p);
                float4 v1 = *(const float4*)(p + 4);
                float xf[8] = {v0.x, v0.y, v0.z, v0.w, v1.x, v1.y, v1.z, v1.w};
                if (kg == 0) {   // wave-uniform: only wave 0 accumulates ||x||^2
                    #pragma unroll
                    for (int i = 0; i < 8; ++i) sx = fmaf(xf[i], xf[i], sx);
                }
                bf16x8 xa, xb, xc;
                split3(xf, xa, xb, xc);
                acc[rt][0] = __builtin_amdgcn_mfma_f32_16x16x32_bf16(xa, ea[0][ch], acc[rt][0], 0, 0, 0);
                acc[rt][1] = __builtin_amdgcn_mfma_f32_16x16x32_bf16(xa, ea[1][ch], acc[rt][1], 0, 0, 0);
                acc[rt][0] = __builtin_amdgcn_mfma_f32_16x16x32_bf16(xa, eb[0][ch], acc[rt][0], 0, 0, 0);
                acc[rt][1] = __builtin_amdgcn_mfma_f32_16x16x32_bf16(xa, eb[1][ch], acc[rt][1], 0, 0, 0);
                acc[rt][0] = __builtin_amdgcn_mfma_f32_16x16x32_bf16(xb, ea[0][ch], acc[rt][0], 0, 0, 0);
                acc[rt][1] = __builtin_amdgcn_mfma_f32_16x16x32_bf16(xb, ea[1][ch], acc[rt][1], 0, 0, 0);
                acc[rt][0] = __builtin_amdgcn_mfma_f32_16x16x32_bf16(xa, ec[0][ch], acc[rt][0], 0, 0, 0);
                acc[rt][1] = __builtin_amdgcn_mfma_f32_16x16x32_bf16(xa, ec[1][ch], acc[rt][1], 0, 0, 0);
                acc[rt][0] = __builtin_amdgcn_mfma_f32_16x16x32_bf16(xc, ea[0][ch], acc[rt][0], 0, 0, 0);
                acc[rt][1] = __builtin_amdgcn_mfma_f32_16x16x32_bf16(xc, ea[1][ch], acc[rt][1], 0, 0, 0);
                acc[rt][0] = __builtin_amdgcn_mfma_f32_16x16x32_bf16(xb, eb[0][ch], acc[rt][0], 0, 0, 0);
                acc[rt][1] = __builtin_amdgcn_mfma_f32_16x16x32_bf16(xb, eb[1][ch], acc[rt][1], 0, 0, 0);
            }
        }
        __syncthreads();   // keep the 4 waves' X streams temporally close (L1/L2 reuse)
    }

    // ---- per-row argmin: t = ||e||^2 - 2*dot; in-lane over 2 col-tiles, then
    // 4-step butterfly across the 16 lanes holding the same rows ----
    const float* sep = ws + 256 + kg * 32;
    const float se0 = sep[l4];
    const float se1 = sep[l4 + 16];
    const int   c0  = kg * 32 + l4;

    #pragma unroll
    for (int rt = 0; rt < 8; ++rt) {
        #pragma unroll
        for (int r = 0; r < 4; ++r) {
            float t0 = fmaf(-2.0f, acc[rt][0][r], se0);
            float t1 = fmaf(-2.0f, acc[rt][1][r], se1);
            float t; int ci;
            if (t1 < t0) { t = t1; ci = c0 + 16; } else { t = t0; ci = c0; }
            #pragma unroll
            for (int m = 1; m <= 8; m <<= 1) {
                float tv = __shfl_xor(t, m);
                int   cv = __shfl_xor(ci, m);
                if (tv < t || (tv == t && cv < ci)) { t = tv; ci = cv; }
            }
            if (l4 == 0) {
                int rl = rt * 16 + g * 4 + r;
                rd[kg][rl] = t;
                ri[kg][rl] = ci;
            }
        }
    }

    if (kg == 0) {   // sum ||x||^2 over the block's rows (wave 0 loaded all of them)
        #pragma unroll
        for (int m = 1; m <= 32; m <<= 1) sx += __shfl_xor(sx, m);
        if (lane == 0) atomicAdd(&ws[0], sx);
    }
    __syncthreads();

    // ---- cross-wave combine (kg ascending, strict < keeps first-index semantics) ----
    if (tid < RPB) {
        float dm = rd[0][tid]; int ix = ri[0][tid];
        #pragma unroll
        for (int gg = 1; gg < 4; ++gg) {
            float t = rd[gg][tid];
            if (t < dm) { dm = t; ix = ri[gg][tid]; }
        }
        idxs[tid] = ix;
        out[OFF_IDX + r0 + tid] = (float)ix;
        atomicAdd(&hcnt[ix], 1);
        float v = dm;                                  // ||x||^2 part added separately
        #pragma unroll
        for (int m = 1; m <= 32; m <<= 1) v += __shfl_xor(v, m);
        if ((tid & 63) == 0) atomicAdd(&ws[0], v);
    }
    __syncthreads();
    if (tid < NUM_K && hcnt[tid]) atomicAdd((int*)ws + 64 + tid, hcnt[tid]);

    // ---- write phase ----
    // quantized: 4 rows/iter, dwordx4 stores (4B-aligned type: OFF_Q=1)
    #pragma unroll 4
    for (int it = 0; it < 32; ++it) {
        int r  = it * 4 + (tid >> 6);
        int ix = idxs[r];
        float4 v = *(const float4*)(E + (size_t)ix * DIM + (tid & 63) * 4);
        f4a w = {v.x, v.y, v.z, v.w};
        *(f4a*)(out + OFF_Q + (size_t)(r0 + r) * DIM + (tid & 63) * 4) = w;
    }
    // encodings one-hot: 128 rows x 32 float4 = 4096 slots, 16 iterations
    #pragma unroll 4
    for (int it = 0; it < 16; ++it) {
        int s  = it * BLOCK + tid;
        int r  = s >> 5;
        int c4 = (s & 31) * 4;
        int ix = idxs[r];
        f4a e4;
        e4.x = (c4     == ix) ? 1.0f : 0.0f;
        e4.y = (c4 + 1 == ix) ? 1.0f : 0.0f;
        e4.z = (c4 + 2 == ix) ? 1.0f : 0.0f;
        e4.w = (c4 + 3 == ix) ? 1.0f : 0.0f;
        *(f4a*)(out + OFF_ENC + (size_t)(r0 + r) * NUM_K + c4) = e4;
    }
}

__global__ void vq_final(const float* __restrict__ ws, float* __restrict__ out) {
    int t = threadIdx.x;   // 128 threads
    if (t == 0) out[OFF_LOSS] = 0.25f * (ws[0] / (float)((size_t)NROWS * DIM));
    int c = ((const int*)ws)[64 + t];
    float p = (float)c / (float)NROWS;
    float v = p * logf(p + 1e-10f);
    #pragma unroll
    for (int off = 32; off; off >>= 1) v += __shfl_down(v, off);
    __shared__ float red[2];
    if ((t & 63) == 0) red[t >> 6] = v;
    __syncthreads();
    if (t == 0) out[OFF_PERP] = expf(-(red[0] + red[1]));
}

extern "C" void kernel_launch(void* const* d_in, const int* in_sizes, int n_in,
                              void* d_out, int out_size, void* d_ws, size_t ws_size,
                              hipStream_t stream) {
    const float* X = (const float*)d_in[0];   // [64,2048,256] fp32
    const float* E = (const float*)d_in[1];   // [128,256] fp32
    float* out = (float*)d_out;
    float* ws  = (float*)d_ws;                // needs >= 1536 bytes

    vq_init <<<NUM_K, 64, 0, stream>>>(E, ws);
    vq_main <<<GRID, BLOCK, 0, stream>>>(X, E, ws, out);
    vq_final<<<1, 128, 0, stream>>>(ws, out);
}

// Round 2
// 358.844 us; speedup vs baseline: 1.1793x; 1.1793x over previous
//
#include <hip/hip_runtime.h>
#include <math.h>

#define NUM_K 128
#define DIM   256
#define NROWS (64 * 2048)       // 131072
#define BLOCK 256

// main path: 64 rows/block, wave owns 32 rows x 64 codes
#define RPB   64
#define GRID  (NROWS / RPB)     // 2048
// fallback path (round-1 kernel): 128 rows/block
#define RPB_F 128
#define GRID_F (NROWS / RPB_F)  // 1024

// flat fp32 output offsets (reference tuple order)
#define OFF_LOSS 0u
#define OFF_Q    1u
#define OFF_PERP 33554433u
#define OFF_ENC  33554434u
#define OFF_IDX  50331650u

// ws float layout: [0] loss acc; ints at float-idx [64..191] counts;
// floats [256..383] se[k]; floats [512..] split-E planes (192 KiB)
#define WS_EF_FLOATS 512
#define WS_NEEDED    (WS_EF_FLOATS * 4 + 64 * 3 * 64 * 16)   // 198656 B

typedef __attribute__((ext_vector_type(8))) short bf16x8;   // 8 bf16 (4 VGPRs)
typedef __attribute__((ext_vector_type(4))) float f32x4;    // MFMA acc
typedef float f4a __attribute__((ext_vector_type(4), aligned(4)));  // 4B-aligned stores (OFF_Q=1)

union PackU { uint4 u; bf16x8 v; };

__device__ __forceinline__ bf16x8 pack_hi16(const unsigned int* w) {
  PackU p;
  p.u.x = (w[1] & 0xFFFF0000u) | (w[0] >> 16);
  p.u.y = (w[3] & 0xFFFF0000u) | (w[2] >> 16);
  p.u.z = (w[5] & 0xFFFF0000u) | (w[4] >> 16);
  p.u.w = (w[7] & 0xFFFF0000u) | (w[6] >> 16);
  return p.v;
}

// Exact 3-way truncation split: x = a + b + c, all bf16-representable.
__device__ __forceinline__ void split3(const float* xf, bf16x8& a, bf16x8& b, bf16x8& c) {
  unsigned int ua[8], ub[8], uc[8];
  #pragma unroll
  for (int i = 0; i < 8; ++i) {
    float x = xf[i];
    unsigned int ha = __float_as_uint(x) & 0xFFFF0000u;
    float r1 = x - __uint_as_float(ha);
    unsigned int hb = __float_as_uint(r1) & 0xFFFF0000u;
    float r2 = r1 - __uint_as_float(hb);
    ua[i] = ha; ub[i] = hb; uc[i] = __float_as_uint(r2);
  }
  a = pack_hi16(ua); b = pack_hi16(ub); c = pack_hi16(uc);
}

// 128 blocks x 64 lanes: block k computes ||e_k||^2; block 0 zeroes accumulators.
__global__ void vq_init(const float* __restrict__ E, float* __restrict__ ws) {
    int k = blockIdx.x, lane = threadIdx.x;
    float4 v = *(const float4*)(E + (size_t)k * DIM + lane * 4);
    float s = v.x * v.x + v.y * v.y + v.z * v.z + v.w * v.w;
    #pragma unroll
    for (int off = 32; off; off >>= 1) s += __shfl_down(s, off);
    if (lane == 0) ws[256 + k] = s;
    if (k == 0) {
        if (lane == 0) ws[0] = 0.0f;
        ((int*)ws)[64 + lane]  = 0;
        ((int*)ws)[128 + lane] = 0;
    }
}

// 64 blocks x 64 lanes: precompute split-E in MFMA-fragment-linear layout.
// block b: ch = b>>3 (K-chunk of 32), CT = b&7 (16-code col-tile).
// lane l: code = CT*16 + (l&15), dims = ch*32 + (l>>4)*8 .. +8.
// Store 3 planes (a,b,c) as bf16x8 at EF[(b*3+s)*64 + lane] -> vq_main loads
// are lane-contiguous dwordx4 (perfectly coalesced, L2-resident).
__global__ void vq_esplit(const float* __restrict__ E, float* __restrict__ ws) {
    int b = blockIdx.x, lane = threadIdx.x;
    int code = (b & 7) * 16 + (lane & 15);
    int d0   = (b >> 3) * 32 + (lane >> 4) * 8;
    const float* p = E + (size_t)code * DIM + d0;
    float4 v0 = *(const float4*)(p);
    float4 v1 = *(const float4*)(p + 4);
    float xf[8] = {v0.x, v0.y, v0.z, v0.w, v1.x, v1.y, v1.z, v1.w};
    bf16x8 a, bq, c;
    split3(xf, a, bq, c);
    bf16x8* dst = (bf16x8*)(ws + WS_EF_FLOATS);
    dst[(b * 3 + 0) * 64 + lane] = a;
    dst[(b * 3 + 1) * 64 + lane] = bq;
    dst[(b * 3 + 2) * 64 + lane] = c;
}

// 2048 blocks x 256 threads (4 waves). Wave kg: pr=kg&1 picks code-half
// (64 codes), rh=kg>>1 picks row-half (32 rows). A-frag: lane holds
// X[row=rt*16+(l&15)][k=(l>>4)*8+j]. B-frags loaded pre-split from ws.
// C/D: col=lane&15 (code), row=(lane>>4)*4+reg.
__global__ __launch_bounds__(BLOCK, 3) void vq_main(
        const float* __restrict__ X, const float* __restrict__ E,
        float* ws, float* __restrict__ out) {
    const int tid  = threadIdx.x;
    const int lane = tid & 63;
    const int kg   = __builtin_amdgcn_readfirstlane(tid >> 6);   // 0..3, wave-uniform
    const int pr   = kg & 1;                                     // code-half
    const int rh   = kg >> 1;                                    // row-half
    const int l4   = lane & 15;
    const int g    = lane >> 4;
    const int r0   = blockIdx.x * RPB;

    __shared__ float rd[2][RPB];
    __shared__ int   ri[2][RPB];
    __shared__ int   idxs[RPB];
    __shared__ int   hcnt[NUM_K];
    if (tid < NUM_K) hcnt[tid] = 0;

    const float* xb = X + (size_t)(r0 + rh * 32 + l4) * DIM + g * 8;
    const bf16x8* __restrict__ EF = (const bf16x8*)(ws + WS_EF_FLOATS);

    f32x4 acc[2][4];
    #pragma unroll
    for (int rt = 0; rt < 2; ++rt)
        #pragma unroll
        for (int ct = 0; ct < 4; ++ct) acc[rt][ct] = (f32x4)0.0f;
    float sx = 0.0f;

    // 1-deep X prefetch pipeline
    float4 a00 = *(const float4*)(xb);
    float4 a01 = *(const float4*)(xb + 4);
    float4 a10 = *(const float4*)(xb + 16 * DIM);
    float4 a11 = *(const float4*)(xb + 16 * DIM + 4);

    #pragma unroll
    for (int ch = 0; ch < 8; ++ch) {
        // B-frags for this K-chunk: 12 coalesced dwordx4 from L2-hot split-E
        bf16x8 ef[4][3];
        #pragma unroll
        for (int ct = 0; ct < 4; ++ct) {
            const int CB = (ch * 8 + pr * 4 + ct) * 3;
            #pragma unroll
            for (int s = 0; s < 3; ++s) ef[ct][s] = EF[(CB + s) * 64 + lane];
        }
        float4 c00 = a00, c01 = a01, c10 = a10, c11 = a11;
        if (ch < 7) {                       // issue next chunk's X loads early
            const float* nx = xb + (ch + 1) * 32;
            a00 = *(const float4*)(nx);
            a01 = *(const float4*)(nx + 4);
            a10 = *(const float4*)(nx + 16 * DIM);
            a11 = *(const float4*)(nx + 16 * DIM + 4);
        }
        float x0[8] = {c00.x, c00.y, c00.z, c00.w, c01.x, c01.y, c01.z, c01.w};
        float x1[8] = {c10.x, c10.y, c10.z, c10.w, c11.x, c11.y, c11.z, c11.w};
        if (pr == 0) {   // wave-uniform: one wave per row-half owns ||x||^2
            #pragma unroll
            for (int i = 0; i < 8; ++i) {
                sx = fmaf(x0[i], x0[i], sx);
                sx = fmaf(x1[i], x1[i], sx);
            }
        }
        bf16x8 xa0, xb0, xc0, xa1, xb1, xc1;
        split3(x0, xa0, xb0, xc0);
        split3(x1, xa1, xb1, xc1);
        // 6 exact-split products, interleaved across 8 independent acc chains
#define MF(XP0, XP1, ES)                                                      \
        _Pragma("unroll")                                                     \
        for (int ct = 0; ct < 4; ++ct) {                                      \
            acc[0][ct] = __builtin_amdgcn_mfma_f32_16x16x32_bf16(XP0, ef[ct][ES], acc[0][ct], 0, 0, 0); \
            acc[1][ct] = __builtin_amdgcn_mfma_f32_16x16x32_bf16(XP1, ef[ct][ES], acc[1][ct], 0, 0, 0); \
        }
        MF(xa0, xa1, 0)
        MF(xa0, xa1, 1)
        MF(xb0, xb1, 0)
        MF(xa0, xa1, 2)
        MF(xc0, xc1, 0)
        MF(xb0, xb1, 1)
#undef MF
    }

    // ---- per-row argmin: t = ||e||^2 - 2*dot; in-lane over 4 col-tiles,
    // then 4-step butterfly across the 16 lanes holding the same row ----
    const float* sep = ws + 256 + pr * 64;
    const float se0 = sep[l4];
    const float se1 = sep[l4 + 16];
    const float se2 = sep[l4 + 32];
    const float se3 = sep[l4 + 48];
    const int   cb  = pr * 64 + l4;

    #pragma unroll
    for (int rt = 0; rt < 2; ++rt) {
        #pragma unroll
        for (int r = 0; r < 4; ++r) {
            float t0 = fmaf(-2.0f, acc[rt][0][r], se0);
            float t1 = fmaf(-2.0f, acc[rt][1][r], se1);
            float t2 = fmaf(-2.0f, acc[rt][2][r], se2);
            float t3 = fmaf(-2.0f, acc[rt][3][r], se3);
            float t = t0; int ci = cb;
            if (t1 < t) { t = t1; ci = cb + 16; }
            if (t2 < t) { t = t2; ci = cb + 32; }
            if (t3 < t) { t = t3; ci = cb + 48; }
            #pragma unroll
            for (int m = 1; m <= 8; m <<= 1) {
                float tv = __shfl_xor(t, m);
                int   cv = __shfl_xor(ci, m);
                if (tv < t || (tv == t && cv < ci)) { t = tv; ci = cv; }
            }
            if (l4 == 0) {
                int rl = rh * 32 + rt * 16 + g * 4 + r;
                rd[pr][rl] = t;
                ri[pr][rl] = ci;
            }
        }
    }

    if (pr == 0) {   // each element of the wave's 32 rows counted exactly once
        #pragma unroll
        for (int m = 1; m <= 32; m <<= 1) sx += __shfl_xor(sx, m);
        if (lane == 0) atomicAdd(&ws[0], sx);
    }
    __syncthreads();

    // ---- cross-pair combine (pr ascending, strict < keeps first-index) ----
    if (tid < RPB) {
        float dm = rd[0][tid]; int ix = ri[0][tid];
        float t  = rd[1][tid];
        if (t < dm) { dm = t; ix = ri[1][tid]; }
        idxs[tid] = ix;
        out[OFF_IDX + r0 + tid] = (float)ix;
        atomicAdd(&hcnt[ix], 1);
        float v = dm;                                  // ||x||^2 added separately
        #pragma unroll
        for (int m = 1; m <= 32; m <<= 1) v += __shfl_xor(v, m);
        if (tid == 0) atomicAdd(&ws[0], v);
    }
    __syncthreads();
    if (tid < NUM_K && hcnt[tid]) atomicAdd((int*)ws + 64 + tid, hcnt[tid]);

    // ---- write phase ----
    // quantized: 4 rows/iter, dwordx4 stores (4B-aligned type: OFF_Q=1)
    #pragma unroll 4
    for (int it = 0; it < 16; ++it) {
        int r  = it * 4 + (tid >> 6);
        int ix = idxs[r];
        float4 v = *(const float4*)(E + (size_t)ix * DIM + (tid & 63) * 4);
        f4a w = {v.x, v.y, v.z, v.w};
        *(f4a*)(out + OFF_Q + (size_t)(r0 + r) * DIM + (tid & 63) * 4) = w;
    }
    // encodings one-hot: 64 rows x 32 float4 = 2048 slots, 8 iterations
    #pragma unroll 4
    for (int it = 0; it < 8; ++it) {
        int s  = it * BLOCK + tid;
        int r  = s >> 5;
        int c4 = (s & 31) * 4;
        int ix = idxs[r];
        f4a e4;
        e4.x = (c4     == ix) ? 1.0f : 0.0f;
        e4.y = (c4 + 1 == ix) ? 1.0f : 0.0f;
        e4.z = (c4 + 2 == ix) ? 1.0f : 0.0f;
        e4.w = (c4 + 3 == ix) ? 1.0f : 0.0f;
        *(f4a*)(out + OFF_ENC + (size_t)(r0 + r) * NUM_K + c4) = e4;
    }
}

// ---------- fallback (round-1 kernel, used only if ws_size < WS_NEEDED) ----------
__global__ __launch_bounds__(BLOCK, 2) void vq_main_f(
        const float* __restrict__ X, const float* __restrict__ E,
        float* ws, float* __restrict__ out) {
    const int tid  = threadIdx.x;
    const int lane = tid & 63;
    const int kg   = __builtin_amdgcn_readfirstlane(tid >> 6);
    const int l4   = lane & 15;
    const int g    = lane >> 4;
    const int r0   = blockIdx.x * RPB_F;

    __shared__ float rd[4][RPB_F];
    __shared__ int   ri[4][RPB_F];
    __shared__ int   idxs[RPB_F];
    __shared__ int   hcnt[NUM_K];
    if (tid < NUM_K) hcnt[tid] = 0;

    const float* xp = X + (size_t)(r0 + l4) * DIM + g * 8;
    const float* ep = E + (size_t)(kg * 32 + l4) * DIM + g * 8;

    f32x4 acc[8][2];
    #pragma unroll
    for (int rt = 0; rt < 8; ++rt) { acc[rt][0] = (f32x4)0.0f; acc[rt][1] = (f32x4)0.0f; }
    float sx = 0.0f;

    #pragma unroll 1
    for (int half = 0; half < 2; ++half) {
        const int kbase = half * 128;
        bf16x8 ea[2][4], eb[2][4], ec[2][4];
        #pragma unroll
        for (int ct = 0; ct < 2; ++ct) {
            #pragma unroll
            for (int ch = 0; ch < 4; ++ch) {
                const float* p = ep + (size_t)ct * 16 * DIM + kbase + ch * 32;
                float4 v0 = *(const float4*)(p);
                float4 v1 = *(const float4*)(p + 4);
                float xf[8] = {v0.x, v0.y, v0.z, v0.w, v1.x, v1.y, v1.z, v1.w};
                split3(xf, ea[ct][ch], eb[ct][ch], ec[ct][ch]);
            }
        }
        #pragma unroll
        for (int rt = 0; rt < 8; ++rt) {
            #pragma unroll
            for (int ch = 0; ch < 4; ++ch) {
                const float* p = xp + (size_t)rt * 16 * DIM + kbase + ch * 32;
                float4 v0 = *(const float4*)(p);
                float4 v1 = *(const float4*)(p + 4);
                float xf[8] = {v0.x, v0.y, v0.z, v0.w, v1.x, v1.y, v1.z, v1.w};
                if (kg == 0) {
                    #pragma unroll
                    for (int i = 0; i < 8; ++i) sx = fmaf(xf[i], xf[i], sx);
                }
                bf16x8 xa, xb, xc;
                split3(xf, xa, xb, xc);
                acc[rt][0] = __builtin_amdgcn_mfma_f32_16x16x32_bf16(xa, ea[0][ch], acc[rt][0], 0, 0, 0);
                acc[rt][1] = __builtin_amdgcn_mfma_f32_16x16x32_bf16(xa, ea[1][ch], acc[rt][1], 0, 0, 0);
                acc[rt][0] = __builtin_amdgcn_mfma_f32_16x16x32_bf16(xa, eb[0][ch], acc[rt][0], 0, 0, 0);
                acc[rt][1] = __builtin_amdgcn_mfma_f32_16x16x32_bf16(xa, eb[1][ch], acc[rt][1], 0, 0, 0);
                acc[rt][0] = __builtin_amdgcn_mfma_f32_16x16x32_bf16(xb, ea[0][ch], acc[rt][0], 0, 0, 0);
                acc[rt][1] = __builtin_amdgcn_mfma_f32_16x16x32_bf16(xb, ea[1][ch], acc[rt][1], 0, 0, 0);
                acc[rt][0] = __builtin_amdgcn_mfma_f32_16x16x32_bf16(xa, ec[0][ch], acc[rt][0], 0, 0, 0);
                acc[rt][1] = __builtin_amdgcn_mfma_f32_16x16x32_bf16(xa, ec[1][ch], acc[rt][1], 0, 0, 0);
                acc[rt][0] = __builtin_amdgcn_mfma_f32_16x16x32_bf16(xc, ea[0][ch], acc[rt][0], 0, 0, 0);
                acc[rt][1] = __builtin_amdgcn_mfma_f32_16x16x32_bf16(xc, ea[1][ch], acc[rt][1], 0, 0, 0);
                acc[rt][0] = __builtin_amdgcn_mfma_f32_16x16x32_bf16(xb, eb[0][ch], acc[rt][0], 0, 0, 0);
                acc[rt][1] = __builtin_amdgcn_mfma_f32_16x16x32_bf16(xb, eb[1][ch], acc[rt][1], 0, 0, 0);
            }
        }
        __syncthreads();
    }

    const float* sep = ws + 256 + kg * 32;
    const float se0 = sep[l4];
    const float se1 = sep[l4 + 16];
    const int   c0  = kg * 32 + l4;

    #pragma unroll
    for (int rt = 0; rt < 8; ++rt) {
        #pragma unroll
        for (int r = 0; r < 4; ++r) {
            float t0 = fmaf(-2.0f, acc[rt][0][r], se0);
            float t1 = fmaf(-2.0f, acc[rt][1][r], se1);
            float t; int ci;
            if (t1 < t0) { t = t1; ci = c0 + 16; } else { t = t0; ci = c0; }
            #pragma unroll
            for (int m = 1; m <= 8; m <<= 1) {
                float tv = __shfl_xor(t, m);
                int   cv = __shfl_xor(ci, m);
                if (tv < t || (tv == t && cv < ci)) { t = tv; ci = cv; }
            }
            if (l4 == 0) {
                int rl = rt * 16 + g * 4 + r;
                rd[kg][rl] = t;
                ri[kg][rl] = ci;
            }
        }
    }

    if (kg == 0) {
        #pragma unroll
        for (int m = 1; m <= 32; m <<= 1) sx += __shfl_xor(sx, m);
        if (lane == 0) atomicAdd(&ws[0], sx);
    }
    __syncthreads();

    if (tid < RPB_F) {
        float dm = rd[0][tid]; int ix = ri[0][tid];
        #pragma unroll
        for (int gg = 1; gg < 4; ++gg) {
            float t = rd[gg][tid];
            if (t < dm) { dm = t; ix = ri[gg][tid]; }
        }
        idxs[tid] = ix;
        out[OFF_IDX + r0 + tid] = (float)ix;
        atomicAdd(&hcnt[ix], 1);
        float v = dm;
        #pragma unroll
        for (int m = 1; m <= 32; m <<= 1) v += __shfl_xor(v, m);
        if ((tid & 63) == 0) atomicAdd(&ws[0], v);
    }
    __syncthreads();
    if (tid < NUM_K && hcnt[tid]) atomicAdd((int*)ws + 64 + tid, hcnt[tid]);

    #pragma unroll 4
    for (int it = 0; it < 32; ++it) {
        int r  = it * 4 + (tid >> 6);
        int ix = idxs[r];
        float4 v = *(const float4*)(E + (size_t)ix * DIM + (tid & 63) * 4);
        f4a w = {v.x, v.y, v.z, v.w};
        *(f4a*)(out + OFF_Q + (size_t)(r0 + r) * DIM + (tid & 63) * 4) = w;
    }
    #pragma unroll 4
    for (int it = 0; it < 16; ++it) {
        int s  = it * BLOCK + tid;
        int r  = s >> 5;
        int c4 = (s & 31) * 4;
        int ix = idxs[r];
        f4a e4;
        e4.x = (c4     == ix) ? 1.0f : 0.0f;
        e4.y = (c4 + 1 == ix) ? 1.0f : 0.0f;
        e4.z = (c4 + 2 == ix) ? 1.0f : 0.0f;
        e4.w = (c4 + 3 == ix) ? 1.0f : 0.0f;
        *(f4a*)(out + OFF_ENC + (size_t)(r0 + r) * NUM_K + c4) = e4;
    }
}

__global__ void vq_final(const float* __restrict__ ws, float* __restrict__ out) {
    int t = threadIdx.x;   // 128 threads
    if (t == 0) out[OFF_LOSS] = 0.25f * (ws[0] / (float)((size_t)NROWS * DIM));
    int c = ((const int*)ws)[64 + t];
    float p = (float)c / (float)NROWS;
    float v = p * logf(p + 1e-10f);
    #pragma unroll
    for (int off = 32; off; off >>= 1) v += __shfl_down(v, off);
    __shared__ float red[2];
    if ((t & 63) == 0) red[t >> 6] = v;
    __syncthreads();
    if (t == 0) out[OFF_PERP] = expf(-(red[0] + red[1]));
}

extern "C" void kernel_launch(void* const* d_in, const int* in_sizes, int n_in,
                              void* d_out, int out_size, void* d_ws, size_t ws_size,
                              hipStream_t stream) {
    const float* X = (const float*)d_in[0];   // [64,2048,256] fp32
    const float* E = (const float*)d_in[1];   // [128,256] fp32
    float* out = (float*)d_out;
    float* ws  = (float*)d_ws;

    vq_init<<<NUM_K, 64, 0, stream>>>(E, ws);
    if (ws_size >= (size_t)WS_NEEDED) {
        vq_esplit<<<64, 64, 0, stream>>>(E, ws);
        vq_main  <<<GRID, BLOCK, 0, stream>>>(X, E, ws, out);
    } else {
        vq_main_f<<<GRID_F, BLOCK, 0, stream>>>(X, E, ws, out);
    }
    vq_final<<<1, 128, 0, stream>>>(ws, out);
}